// Round 6
// baseline (76.669 us; speedup 1.0000x reference)
//
#include <hip/hip_runtime.h>
#include <math.h>
#include <utility>

#define EPSF 1e-12f

constexpr int LLEN = 1024;
constexpr int WMAX = 60;
constexpr int LP   = LLEN - WMAX;   // 964
constexpr int NF   = 158;
constexpr int CHUNK = 64;
constexpr int SPAN  = CHUNK + WMAX; // 124
constexpr int NCH   = (LP + CHUNK - 1) / CHUNK; // 16
constexpr int OBS   = 159;          // LDS row stride (gcd(159-128? ) 159%32=31, coprime w/ 32)

__device__ __forceinline__ float frcp(float x) {
#if __has_builtin(__builtin_amdgcn_rcpf)
  return __builtin_amdgcn_rcpf(x);
#else
  return 1.0f / x;
#endif
}

// Compile-time unrolled for: calls f(integral_constant<int, I0..I0+N-1>)
template<int I0, class F, int... Is>
__device__ __forceinline__ void unroll_impl(F&& f, std::integer_sequence<int, Is...>) {
  (f(std::integral_constant<int, I0 + Is>{}), ...);
}
template<int I0, int N, class F>
__device__ __forceinline__ void unroll_for(F&& f) {
  unroll_impl<I0>(f, std::make_integer_sequence<int, N>{});
}

// Fully-unrolled bitonic sort on a compile-time-size register array.
template<int N>
__device__ __forceinline__ void bitonic_sort(float (&a)[N]) {
#pragma unroll
  for (int k = 2; k <= N; k <<= 1) {
#pragma unroll
    for (int j = k >> 1; j > 0; j >>= 1) {
#pragma unroll
      for (int i = 0; i < N; ++i) {
        int l = i ^ j;
        if (l > i) {
          float x = a[i], y = a[l];
          float mn = fminf(x, y), mx = fmaxf(x, y);
          if ((i & k) == 0) { a[i] = mn; a[l] = mx; }
          else              { a[i] = mx; a[l] = mn; }
        }
      }
    }
  }
}

// Emit all 29 features of window W_ into the LDS row buffer outr[] (runtime
// base + compile-time offsets -> ds_write immediates). Scan accumulators in
// scope; c_ is close[T-W_].
#define EMITW(W_, FI_, TA_) do {                                              \
  constexpr float wf_  = (float)(W_);                                         \
  constexpr float inw_ = 1.0f / wf_;                                          \
  constexpr float tm_  = (W_ - 1) * 0.5f;                                     \
  constexpr float tv_  = (float)(((double)(W_) * (W_) - 1.0) / 12.0);         \
  constexpr int   k8_  = (int)(0.8 * (W_ - 1));                               \
  constexpr float f8_  = (float)(0.8 * (W_ - 1) - k8_);                       \
  constexpr int   k2_  = (int)(0.2 * (W_ - 1));                               \
  constexpr float f2_  = (float)(0.2 * (W_ - 1) - k2_);                       \
  float qtlu_ = TA_[k8_] + f8_ * (TA_[k8_ + 1] - TA_[k8_]);                   \
  float qtld_ = TA_[k2_] + f2_ * (TA_[k2_ + 1] - TA_[k2_]);                   \
  float scm_  = sc * inw_;                                                    \
  float ym_   = cl + scm_;                                                    \
  float yvar_ = fmaxf(sc2 * inw_ - scm_ * scm_, 0.f);                         \
  float stdv_ = sqrtf(yvar_);                                                 \
  float skc_  = (wf_ - 1.f) * sc - sic;                                       \
  float cov_  = skc_ * inw_ - tm_ * scm_;                                     \
  float slope_ = cov_ * (1.0f / tv_);                                         \
  float rsqr_  = cov_ * cov_ * frcp(tv_ * yvar_ + EPSF);                      \
  float resi_  = (cl - ym_) - slope_ * tm_;                                   \
  float cnum_ = sclg - sc * slg * inw_;                                       \
  float cden_ = sqrtf(fmaxf(sc2 - sc * sc * inw_, 0.f) *                      \
                      fmaxf(slg2 - slg * slg * inw_, 0.f)) + EPSF;            \
  float corr_ = cnum_ * frcp(cden_);                                          \
  float dnum_ = srl - sr * sl * inw_;                                         \
  float dden_ = sqrtf(fmaxf(sr2 - sr * sr * inw_, 0.f) *                      \
                      fmaxf(sl2 - sl * sl * inw_, 0.f)) + EPSF;               \
  float cord_ = dnum_ * frcp(dden_);                                          \
  float absd_ = sp + sn;    float ra_ = frcp(absd_ + EPSF);                   \
  float sump_ = sp * ra_,  sumn_ = sn * ra_;                                  \
  float absv_ = dvp + dvn;  float rv_ = frcp(absv_ + EPSF);                   \
  float vsump_ = dvp * rv_, vsumn_ = dvn * rv_;                               \
  float vmean_ = sv * inw_;                                                   \
  float vvar_  = fmaxf(sv2 * inw_ - vmean_ * vmean_, 0.f);                    \
  float wmean_ = sw * inw_;                                                   \
  float wvar_  = fmaxf(sw2 * inw_ - wmean_ * wmean_, 0.f);                    \
  float cntp_ = (float)npos * inw_, cntn_ = (float)nneg * inw_;               \
  float imaxf_ = (float)((W_ - 1) - imax) * inw_;                             \
  float iminf_ = (float)((W_ - 1) - imin) * inw_;                             \
  outr[FI_ + 0]  = c_ * rcl;                                                  \
  outr[FI_ + 1]  = ym_ * rcl;                                                 \
  outr[FI_ + 2]  = stdv_ * rcl;                                               \
  outr[FI_ + 3]  = slope_ * rcl;                                              \
  outr[FI_ + 4]  = rsqr_;                                                     \
  outr[FI_ + 5]  = resi_ * rcl;                                               \
  outr[FI_ + 6]  = hmax * rcl;                                                \
  outr[FI_ + 7]  = lmin * rcl;                                                \
  outr[FI_ + 8]  = qtlu_ * rcl;                                               \
  outr[FI_ + 9]  = qtld_ * rcl;                                               \
  outr[FI_ + 10] = (float)cntle * inw_;                                       \
  outr[FI_ + 11] = (cl - lmin) * frcp(hmax - lmin + EPSF);                    \
  outr[FI_ + 12] = imaxf_;                                                    \
  outr[FI_ + 13] = iminf_;                                                    \
  outr[FI_ + 14] = imaxf_ - iminf_;                                           \
  outr[FI_ + 15] = corr_;                                                     \
  outr[FI_ + 16] = cord_;                                                     \
  outr[FI_ + 17] = cntp_;                                                     \
  outr[FI_ + 18] = cntn_;                                                     \
  outr[FI_ + 19] = cntp_ - cntn_;                                             \
  outr[FI_ + 20] = sump_;                                                     \
  outr[FI_ + 21] = sumn_;                                                     \
  outr[FI_ + 22] = sump_ - sumn_;                                             \
  outr[FI_ + 23] = vmean_ * rvA;                                              \
  outr[FI_ + 24] = sqrtf(vvar_) * rvA;                                        \
  outr[FI_ + 25] = sqrtf(wvar_) * frcp(wmean_ + EPSF);                        \
  outr[FI_ + 26] = vsump_;                                                    \
  outr[FI_ + 27] = vsumn_;                                                    \
  outr[FI_ + 28] = vsump_ - vsumn_;                                           \
} while (0)

__global__ __launch_bounds__(64, 2)
void factor_kernel(const float* __restrict__ x, float* __restrict__ out, int B)
{
  __shared__ float cs[SPAN], hs[SPAN], ls[SPAN], vs[SPAN], lgs[SPAN];
  __shared__ float ob[CHUNK * OBS];   // 64 rows x 159 stride = 40704 B

  const int b    = blockIdx.x / NCH;
  const int ch   = blockIdx.x % NCH;
  const int t0   = WMAX + ch * CHUNK;              // first global t of chunk
  const int clen = min(CHUNK, LP - ch * CHUNK);
  const int base = t0 - WMAX;                      // global index of local 0
  const int span = clen + WMAX;
  const int tid  = threadIdx.x;

  // stage raw series
  for (int u = tid; u < span; u += 64) {
    const float* p = x + (size_t)(b * LLEN + base + u) * 6;
    float hv = p[1], lv = p[2], cv = p[3], vv = p[4];
    cs[u] = cv; hs[u] = hv; ls[u] = lv; vs[u] = vv;
    lgs[u] = logf(vv + 1.f);
  }
  __syncthreads();

  if (tid < clen) {
    const int tg = t0 + tid;       // global t

    const float* cb = cs  + tid;   // cb[WMAX - i] == series[T - i]
    const float* hb = hs  + tid;
    const float* lb = ls  + tid;
    const float* vb = vs  + tid;
    const float* gb = lgs + tid;

    const float cl  = cb[WMAX];
    const float vol = vb[WMAX];
    const float lgT = gb[WMAX];
    const float rcl = 1.0f / cl;
    const float rvA = 1.0f / (vol + EPSF);

    float* outr = ob + tid * OBS;  // LDS-resident output row

    // ---- base features ----
    {
      const float* p = x + (size_t)(b * LLEN + tg) * 6;
      float opn = p[0], vwp = p[5];
      float hi = hb[WMAX], lo = lb[WMAX];
      float hl = hi - lo + EPSF;
      float rhl = frcp(hl);
      float ro  = 1.0f / opn;
      float mx_oc = fmaxf(opn, cl), mn_oc = fminf(opn, cl);
      float body2 = 2.f * cl - hi - lo;
      outr[0]  = (cl - opn) * ro;
      outr[1]  = (hi - lo) * ro;
      outr[2]  = (cl - opn) * rhl;
      outr[3]  = (hi - mx_oc) * ro;
      outr[4]  = (hi - mx_oc) * rhl;
      outr[5]  = (mn_oc - lo) * ro;
      outr[6]  = (mn_oc - lo) * rhl;
      outr[7]  = body2 * ro;
      outr[8]  = body2 * rhl;
      outr[9]  = opn * rcl;
      outr[10] = hi * rcl;
      outr[11] = lo * rcl;
      outr[12] = vwp * rcl;
    }

    // ---- fused backward scan, compile-time segmented ----
    float sarr[64];
    sarr[60] = sarr[61] = sarr[62] = sarr[63] = INFINITY;

    float sc = 0.f, sc2 = 0.f, sic = 0.f;
    float sv = 0.f, sv2 = 0.f;
    float slg = 0.f, slg2 = 0.f, sclg = 0.f;
    int   cntle = 0;
    float hmax = -INFINITY, lmin = INFINITY;
    int   imax = 0, imin = 0;
    float sr = 0.f, sr2 = 0.f, sl = 0.f, sl2 = 0.f, srl = 0.f;
    float sw = 0.f, sw2 = 0.f;
    float sp = 0.f, sn = 0.f, dvp = 0.f, dvn = 0.f;
    int   npos = 0, nneg = 0;
    float pv_c = 0.f, pv_v = 0.f;
    float c_ = 0.f, h_ = 0.f, l_ = 0.f, v_ = 0.f, lg_ = 0.f;

    // load element i (= series index T-i) + pass2 pair (T-i, T-i+1) for i>=1
    auto load2 = [&](auto ic) {
      constexpr int i = decltype(ic)::value;
      constexpr int q = WMAX - i;
      c_ = cb[q]; v_ = vb[q];
      if constexpr (i < WMAX) { h_ = hb[q]; l_ = lb[q]; lg_ = gb[q]; }
      if constexpr (i >= 1) {
        float d   = pv_c - c_;
        float dv  = pv_v - v_;
        float r   = pv_c * frcp(c_) - 1.f;
        float lcv = __logf(pv_v * frcp(v_ + EPSF) + 1.f);
        float wvv = fabsf(r) * pv_v;
        sr += r;   sr2 = fmaf(r, r, sr2);
        sl += lcv; sl2 = fmaf(lcv, lcv, sl2); srl = fmaf(r, lcv, srl);
        sw += wvv; sw2 = fmaf(wvv, wvv, sw2);
        npos += (d > 0.f) ? 1 : 0;
        nneg += (d < 0.f) ? 1 : 0;
        sp  += fmaxf(d, 0.f);  sn  += fmaxf(-d, 0.f);
        dvp += fmaxf(dv, 0.f); dvn += fmaxf(-dv, 0.f);
      }
    };
    // pass1 for element i
    auto p1 = [&](auto ic) {
      constexpr int i = decltype(ic)::value;
      float cd = c_ - cl;
      sc += cd; sc2 = fmaf(cd, cd, sc2); sic = fmaf((float)i, cd, sic);
      cntle += (c_ <= cl) ? 1 : 0;
      if (h_ >= hmax) { hmax = h_; imax = i; }
      if (l_ <= lmin) { lmin = l_; imin = i; }
      sv += v_; sv2 = fmaf(v_, v_, sv2);
      float ld = lg_ - lgT;
      slg += ld; slg2 = fmaf(ld, ld, slg2); sclg = fmaf(cd, ld, sclg);
      sarr[i] = c_;
      pv_c = c_; pv_v = v_;
    };
    auto step = [&](auto ic) { load2(ic); p1(ic); };

    unroll_for<0, 5>(step);                       // i = 0..4
    load2(std::integral_constant<int, 5>{});
    {
      float t[8];
      unroll_for<0, 8>([&](auto q) {
        constexpr int qq = decltype(q)::value;
        t[qq] = (qq < 5) ? sarr[qq] : INFINITY;
      });
      bitonic_sort<8>(t);
      EMITW(5, 13, t);
    }
    p1(std::integral_constant<int, 5>{});

    unroll_for<6, 4>(step);                       // i = 6..9
    load2(std::integral_constant<int, 10>{});
    {
      float t[16];
      unroll_for<0, 16>([&](auto q) {
        constexpr int qq = decltype(q)::value;
        t[qq] = (qq < 10) ? sarr[qq] : INFINITY;
      });
      bitonic_sort<16>(t);
      EMITW(10, 42, t);
    }
    p1(std::integral_constant<int, 10>{});

    unroll_for<11, 9>(step);                      // i = 11..19
    load2(std::integral_constant<int, 20>{});
    {
      float t[32];
      unroll_for<0, 32>([&](auto q) {
        constexpr int qq = decltype(q)::value;
        t[qq] = (qq < 20) ? sarr[qq] : INFINITY;
      });
      bitonic_sort<32>(t);
      EMITW(20, 71, t);
    }
    p1(std::integral_constant<int, 20>{});

    unroll_for<21, 9>(step);                      // i = 21..29
    load2(std::integral_constant<int, 30>{});
    {
      float t[32];
      unroll_for<0, 32>([&](auto q) {
        constexpr int qq = decltype(q)::value;
        t[qq] = (qq < 30) ? sarr[qq] : INFINITY;
      });
      bitonic_sort<32>(t);
      EMITW(30, 100, t);
    }
    p1(std::integral_constant<int, 30>{});

    unroll_for<31, 29>(step);                     // i = 31..59

    // i = 60: pass2 pair (T-60, T-59), sort all 60, emit w=60
    load2(std::integral_constant<int, 60>{});
    bitonic_sort<64>(sarr);
    EMITW(60, 129, sarr);
  }

  // ---- coalesced contiguous flush: block's rows form one linear segment ----
  __syncthreads();
  {
    float* gout = out + ((size_t)b * LP + ch * CHUNK) * NF;
    for (int r = 0; r < clen; ++r) {
      const float* src = ob + r * OBS;
      float* dst = gout + (size_t)r * NF;
#pragma unroll
      for (int k0 = 0; k0 < NF; k0 += 64) {
        int k = k0 + tid;
        if (k0 + 64 <= NF || k < NF) dst[k] = src[k];
      }
    }
  }
}

extern "C" void kernel_launch(void* const* d_in, const int* in_sizes, int n_in,
                              void* d_out, int out_size, void* d_ws, size_t ws_size,
                              hipStream_t stream) {
  const float* x = (const float*)d_in[0];
  float* out = (float*)d_out;
  int B = in_sizes[0] / (LLEN * 6);   // 128
  dim3 grid(B * NCH), block(64);
  hipLaunchKernelGGL(factor_kernel, grid, block, 0, stream, x, out, B);
}

// Round 7
// 55.540 us; speedup vs baseline: 1.3804x; 1.3804x over previous
//
#include <hip/hip_runtime.h>
#include <math.h>
#include <utility>

#define EPSF 1e-12f

constexpr int LLEN = 1024;
constexpr int WMAX = 60;
constexpr int LP   = LLEN - WMAX;   // 964
constexpr int NF   = 158;
constexpr int CHUNK = 64;
constexpr int SPAN  = CHUNK + WMAX; // 124
constexpr int NCH   = (LP + CHUNK - 1) / CHUNK; // 16
constexpr int OBW   = 87;           // LDS row stride; 87%32=23 coprime w/ 32 -> conflict-free
constexpr int PH1   = 71;           // phase-1 width: base(13)+w5(29)+w10(29)

__device__ __forceinline__ float frcp(float x) {
#if __has_builtin(__builtin_amdgcn_rcpf)
  return __builtin_amdgcn_rcpf(x);
#else
  return 1.0f / x;
#endif
}

// Compile-time unrolled for: calls f(integral_constant<int, I0..I0+N-1>)
template<int I0, class F, int... Is>
__device__ __forceinline__ void unroll_impl(F&& f, std::integer_sequence<int, Is...>) {
  (f(std::integral_constant<int, I0 + Is>{}), ...);
}
template<int I0, int N, class F>
__device__ __forceinline__ void unroll_for(F&& f) {
  unroll_impl<I0>(f, std::make_integer_sequence<int, N>{});
}

// Fully-unrolled bitonic sort on a compile-time-size register array.
template<int N>
__device__ __forceinline__ void bitonic_sort(float (&a)[N]) {
#pragma unroll
  for (int k = 2; k <= N; k <<= 1) {
#pragma unroll
    for (int j = k >> 1; j > 0; j >>= 1) {
#pragma unroll
      for (int i = 0; i < N; ++i) {
        int l = i ^ j;
        if (l > i) {
          float x = a[i], y = a[l];
          float mn = fminf(x, y), mx = fmaxf(x, y);
          if ((i & k) == 0) { a[i] = mn; a[l] = mx; }
          else              { a[i] = mx; a[l] = mn; }
        }
      }
    }
  }
}

// Emit all 29 features of window W_ into LDS row buffer outr[] at phase-local
// offset FI_. Scan accumulators in scope; c_ is close[T-W_].
#define EMITW(W_, FI_, TA_) do {                                              \
  constexpr float wf_  = (float)(W_);                                         \
  constexpr float inw_ = 1.0f / wf_;                                          \
  constexpr float tm_  = (W_ - 1) * 0.5f;                                     \
  constexpr float tv_  = (float)(((double)(W_) * (W_) - 1.0) / 12.0);         \
  constexpr int   k8_  = (int)(0.8 * (W_ - 1));                               \
  constexpr float f8_  = (float)(0.8 * (W_ - 1) - k8_);                       \
  constexpr int   k2_  = (int)(0.2 * (W_ - 1));                               \
  constexpr float f2_  = (float)(0.2 * (W_ - 1) - k2_);                       \
  float qtlu_ = TA_[k8_] + f8_ * (TA_[k8_ + 1] - TA_[k8_]);                   \
  float qtld_ = TA_[k2_] + f2_ * (TA_[k2_ + 1] - TA_[k2_]);                   \
  float scm_  = sc * inw_;                                                    \
  float ym_   = cl + scm_;                                                    \
  float yvar_ = fmaxf(sc2 * inw_ - scm_ * scm_, 0.f);                         \
  float stdv_ = sqrtf(yvar_);                                                 \
  float skc_  = (wf_ - 1.f) * sc - sic;                                       \
  float cov_  = skc_ * inw_ - tm_ * scm_;                                     \
  float slope_ = cov_ * (1.0f / tv_);                                         \
  float rsqr_  = cov_ * cov_ * frcp(tv_ * yvar_ + EPSF);                      \
  float resi_  = (cl - ym_) - slope_ * tm_;                                   \
  float cnum_ = sclg - sc * slg * inw_;                                       \
  float cden_ = sqrtf(fmaxf(sc2 - sc * sc * inw_, 0.f) *                      \
                      fmaxf(slg2 - slg * slg * inw_, 0.f)) + EPSF;            \
  float corr_ = cnum_ * frcp(cden_);                                          \
  float dnum_ = srl - sr * sl * inw_;                                         \
  float dden_ = sqrtf(fmaxf(sr2 - sr * sr * inw_, 0.f) *                      \
                      fmaxf(sl2 - sl * sl * inw_, 0.f)) + EPSF;               \
  float cord_ = dnum_ * frcp(dden_);                                          \
  float absd_ = sp + sn;    float ra_ = frcp(absd_ + EPSF);                   \
  float sump_ = sp * ra_,  sumn_ = sn * ra_;                                  \
  float absv_ = dvp + dvn;  float rv_ = frcp(absv_ + EPSF);                   \
  float vsump_ = dvp * rv_, vsumn_ = dvn * rv_;                               \
  float vmean_ = sv * inw_;                                                   \
  float vvar_  = fmaxf(sv2 * inw_ - vmean_ * vmean_, 0.f);                    \
  float wmean_ = sw * inw_;                                                   \
  float wvar_  = fmaxf(sw2 * inw_ - wmean_ * wmean_, 0.f);                    \
  float cntp_ = (float)npos * inw_, cntn_ = (float)nneg * inw_;               \
  float imaxf_ = (float)((W_ - 1) - imax) * inw_;                             \
  float iminf_ = (float)((W_ - 1) - imin) * inw_;                             \
  outr[FI_ + 0]  = c_ * rcl;                                                  \
  outr[FI_ + 1]  = ym_ * rcl;                                                 \
  outr[FI_ + 2]  = stdv_ * rcl;                                               \
  outr[FI_ + 3]  = slope_ * rcl;                                              \
  outr[FI_ + 4]  = rsqr_;                                                     \
  outr[FI_ + 5]  = resi_ * rcl;                                               \
  outr[FI_ + 6]  = hmax * rcl;                                                \
  outr[FI_ + 7]  = lmin * rcl;                                                \
  outr[FI_ + 8]  = qtlu_ * rcl;                                               \
  outr[FI_ + 9]  = qtld_ * rcl;                                               \
  outr[FI_ + 10] = (float)cntle * inw_;                                       \
  outr[FI_ + 11] = (cl - lmin) * frcp(hmax - lmin + EPSF);                    \
  outr[FI_ + 12] = imaxf_;                                                    \
  outr[FI_ + 13] = iminf_;                                                    \
  outr[FI_ + 14] = imaxf_ - iminf_;                                           \
  outr[FI_ + 15] = corr_;                                                     \
  outr[FI_ + 16] = cord_;                                                     \
  outr[FI_ + 17] = cntp_;                                                     \
  outr[FI_ + 18] = cntn_;                                                     \
  outr[FI_ + 19] = cntp_ - cntn_;                                             \
  outr[FI_ + 20] = sump_;                                                     \
  outr[FI_ + 21] = sumn_;                                                     \
  outr[FI_ + 22] = sump_ - sumn_;                                             \
  outr[FI_ + 23] = vmean_ * rvA;                                              \
  outr[FI_ + 24] = sqrtf(vvar_) * rvA;                                        \
  outr[FI_ + 25] = sqrtf(wvar_) * frcp(wmean_ + EPSF);                        \
  outr[FI_ + 26] = vsump_;                                                    \
  outr[FI_ + 27] = vsumn_;                                                    \
  outr[FI_ + 28] = vsump_ - vsumn_;                                           \
} while (0)

__global__ __launch_bounds__(128, 3)
void factor_kernel(const float* __restrict__ x, float* __restrict__ out, int B)
{
  __shared__ float cs[SPAN], hs[SPAN], ls[SPAN], vs[SPAN], lgs[SPAN];
  __shared__ float ob[CHUNK * OBW];   // 64 rows x 87 = 22272 B, reused across phases

  const int b    = blockIdx.x / NCH;
  const int ch   = blockIdx.x % NCH;
  const int t0   = WMAX + ch * CHUNK;              // first global t of chunk
  const int clen = min(CHUNK, LP - ch * CHUNK);
  const int base = t0 - WMAX;                      // global index of local 0
  const int span = clen + WMAX;
  const int tid  = threadIdx.x;
  const int tt   = tid & 63;       // point within chunk
  const int role = tid >> 6;       // 0: base+w60, 1: w5..w30 (wave-uniform)

  // stage raw series
  for (int u = tid; u < span; u += 128) {
    const float* p = x + (size_t)(b * LLEN + base + u) * 6;
    float hv = p[1], lv = p[2], cv = p[3], vv = p[4];
    cs[u] = cv; hs[u] = hv; ls[u] = lv; vs[u] = vv;
    lgs[u] = logf(vv + 1.f);
  }
  __syncthreads();

  const bool active = (tt < clen);
  const int tg = t0 + tt;          // global t

  const float* cb = cs  + tt;      // cb[WMAX - i] == series[T - i]
  const float* hb = hs  + tt;
  const float* lb = ls  + tt;
  const float* vb = vs  + tt;
  const float* gb = lgs + tt;

  const float cl  = cb[WMAX];
  const float vol = vb[WMAX];
  const float lgT = gb[WMAX];
  const float rcl = 1.0f / cl;
  const float rvA = 1.0f / (vol + EPSF);

  float* outr = ob + tt * OBW;     // LDS-resident output row (phase-local)

  // ---- scan state (lives in registers across barriers) ----
  float sarr[64];
  sarr[60] = sarr[61] = sarr[62] = sarr[63] = INFINITY;

  float sc = 0.f, sc2 = 0.f, sic = 0.f;
  float sv = 0.f, sv2 = 0.f;
  float slg = 0.f, slg2 = 0.f, sclg = 0.f;
  int   cntle = 0;
  float hmax = -INFINITY, lmin = INFINITY;
  int   imax = 0, imin = 0;
  float sr = 0.f, sr2 = 0.f, sl = 0.f, sl2 = 0.f, srl = 0.f;
  float sw = 0.f, sw2 = 0.f;
  float sp = 0.f, sn = 0.f, dvp = 0.f, dvn = 0.f;
  int   npos = 0, nneg = 0;
  float pv_c = 0.f, pv_v = 0.f;
  float c_ = 0.f, h_ = 0.f, l_ = 0.f, v_ = 0.f, lg_ = 0.f;

  // load element i (= series index T-i) + pass2 pair (T-i, T-i+1) for i>=1
  auto load2 = [&](auto ic) {
    constexpr int i = decltype(ic)::value;
    constexpr int q = WMAX - i;
    c_ = cb[q]; v_ = vb[q];
    if constexpr (i < WMAX) { h_ = hb[q]; l_ = lb[q]; lg_ = gb[q]; }
    if constexpr (i >= 1) {
      float d   = pv_c - c_;
      float dv  = pv_v - v_;
      float r   = pv_c * frcp(c_) - 1.f;
      float lcv = __logf(pv_v * frcp(v_ + EPSF) + 1.f);
      float wvv = fabsf(r) * pv_v;
      sr += r;   sr2 = fmaf(r, r, sr2);
      sl += lcv; sl2 = fmaf(lcv, lcv, sl2); srl = fmaf(r, lcv, srl);
      sw += wvv; sw2 = fmaf(wvv, wvv, sw2);
      npos += (d > 0.f) ? 1 : 0;
      nneg += (d < 0.f) ? 1 : 0;
      sp  += fmaxf(d, 0.f);  sn  += fmaxf(-d, 0.f);
      dvp += fmaxf(dv, 0.f); dvn += fmaxf(-dv, 0.f);
    }
  };
  // pass1 for element i
  auto p1 = [&](auto ic) {
    constexpr int i = decltype(ic)::value;
    float cd = c_ - cl;
    sc += cd; sc2 = fmaf(cd, cd, sc2); sic = fmaf((float)i, cd, sic);
    cntle += (c_ <= cl) ? 1 : 0;
    if (h_ >= hmax) { hmax = h_; imax = i; }
    if (l_ <= lmin) { lmin = l_; imin = i; }
    sv += v_; sv2 = fmaf(v_, v_, sv2);
    float ld = lg_ - lgT;
    slg += ld; slg2 = fmaf(ld, ld, slg2); sclg = fmaf(cd, ld, sclg);
    sarr[i] = c_;
    pv_c = c_; pv_v = v_;
  };
  auto step = [&](auto ic) { load2(ic); p1(ic); };

  // ================= segment 1 (phase-1 features: 0..70) =================
  if (active) {
    if (role == 0) {
      // base features -> outr[0..12]
      const float* p = x + (size_t)(b * LLEN + tg) * 6;
      float opn = p[0], vwp = p[5];
      float hi = hb[WMAX], lo = lb[WMAX];
      float hl = hi - lo + EPSF;
      float rhl = frcp(hl);
      float ro  = 1.0f / opn;
      float mx_oc = fmaxf(opn, cl), mn_oc = fminf(opn, cl);
      float body2 = 2.f * cl - hi - lo;
      outr[0]  = (cl - opn) * ro;
      outr[1]  = (hi - lo) * ro;
      outr[2]  = (cl - opn) * rhl;
      outr[3]  = (hi - mx_oc) * ro;
      outr[4]  = (hi - mx_oc) * rhl;
      outr[5]  = (mn_oc - lo) * ro;
      outr[6]  = (mn_oc - lo) * rhl;
      outr[7]  = body2 * ro;
      outr[8]  = body2 * rhl;
      outr[9]  = opn * rcl;
      outr[10] = hi * rcl;
      outr[11] = lo * rcl;
      outr[12] = vwp * rcl;
      unroll_for<0, 26>(step);                    // i = 0..25
    } else {
      unroll_for<0, 5>(step);                     // i = 0..4
      load2(std::integral_constant<int, 5>{});
      {
        float t[8];
        unroll_for<0, 8>([&](auto q) {
          constexpr int qq = decltype(q)::value;
          t[qq] = (qq < 5) ? sarr[qq] : INFINITY;
        });
        bitonic_sort<8>(t);
        EMITW(5, 13, t);
      }
      p1(std::integral_constant<int, 5>{});
      unroll_for<6, 4>(step);                     // i = 6..9
      load2(std::integral_constant<int, 10>{});
      {
        float t[16];
        unroll_for<0, 16>([&](auto q) {
          constexpr int qq = decltype(q)::value;
          t[qq] = (qq < 10) ? sarr[qq] : INFINITY;
        });
        bitonic_sort<16>(t);
        EMITW(10, 42, t);
      }
      p1(std::integral_constant<int, 10>{});
    }
  }
  __syncthreads();

  // ---- flush phase 1: features 0..70, contiguous coalesced ----
  {
    float* gout = out + ((size_t)b * LP + ch * CHUNK) * NF;
    const int total = clen * PH1;
    for (int n = tid; n < total; n += 128) {
      int r = n / PH1, cc = n - r * PH1;
      gout[(size_t)r * NF + cc] = ob[r * OBW + cc];
    }
  }
  __syncthreads();

  // ================= segment 2 (phase-2 features: 71..157) =================
  if (active) {
    if (role == 0) {
      unroll_for<26, 34>(step);                   // i = 26..59
      load2(std::integral_constant<int, 60>{});
      bitonic_sort<64>(sarr);
      EMITW(60, 58, sarr);                        // features 129..157 -> outr[58..86]
    } else {
      unroll_for<11, 9>(step);                    // i = 11..19
      load2(std::integral_constant<int, 20>{});
      {
        float t[32];
        unroll_for<0, 32>([&](auto q) {
          constexpr int qq = decltype(q)::value;
          t[qq] = (qq < 20) ? sarr[qq] : INFINITY;
        });
        bitonic_sort<32>(t);
        EMITW(20, 0, t);                          // features 71..99 -> outr[0..28]
      }
      p1(std::integral_constant<int, 20>{});
      unroll_for<21, 9>(step);                    // i = 21..29
      load2(std::integral_constant<int, 30>{});
      {
        float t[32];
        unroll_for<0, 32>([&](auto q) {
          constexpr int qq = decltype(q)::value;
          t[qq] = (qq < 30) ? sarr[qq] : INFINITY;
        });
        bitonic_sort<32>(t);
        EMITW(30, 29, t);                         // features 100..128 -> outr[29..57]
      }
      p1(std::integral_constant<int, 30>{});
    }
  }
  __syncthreads();

  // ---- flush phase 2: features 71..157 ----
  {
    float* gout = out + ((size_t)b * LP + ch * CHUNK) * NF + PH1;
    const int total = clen * OBW;
    for (int n = tid; n < total; n += 128) {
      int r = n / OBW, cc = n - r * OBW;
      gout[(size_t)r * NF + cc] = ob[n];
    }
  }
}

extern "C" void kernel_launch(void* const* d_in, const int* in_sizes, int n_in,
                              void* d_out, int out_size, void* d_ws, size_t ws_size,
                              hipStream_t stream) {
  const float* x = (const float*)d_in[0];
  float* out = (float*)d_out;
  int B = in_sizes[0] / (LLEN * 6);   // 128
  dim3 grid(B * NCH), block(128);
  hipLaunchKernelGGL(factor_kernel, grid, block, 0, stream, x, out, B);
}

// Round 8
// 49.457 us; speedup vs baseline: 1.5502x; 1.1230x over previous
//
#include <hip/hip_runtime.h>
#include <math.h>
#include <utility>

#define EPSF 1e-12f

constexpr int LLEN = 1024;
constexpr int WMAX = 60;
constexpr int LP   = LLEN - WMAX;   // 964
constexpr int NF   = 158;
constexpr int CHUNK = 64;
constexpr int SPAN  = CHUNK + WMAX; // 124
constexpr int NCH   = (LP + CHUNK - 1) / CHUNK; // 16
constexpr int OBW   = 87;           // LDS row stride; 87%32=23 coprime w/ 32
constexpr int PH1   = 71;           // phase-1 width: base(13)+w5(29)+w10(29)

__device__ __forceinline__ float frcp(float x) {
#if __has_builtin(__builtin_amdgcn_rcpf)
  return __builtin_amdgcn_rcpf(x);
#else
  return 1.0f / x;
#endif
}

template<int I0, class F, int... Is>
__device__ __forceinline__ void unroll_impl(F&& f, std::integer_sequence<int, Is...>) {
  (f(std::integral_constant<int, I0 + Is>{}), ...);
}
template<int I0, int N, class F>
__device__ __forceinline__ void unroll_for(F&& f) {
  unroll_impl<I0>(f, std::make_integer_sequence<int, N>{});
}

// Fully-unrolled bitonic sort.
template<int N>
__device__ __forceinline__ void bitonic_sort(float (&a)[N]) {
#pragma unroll
  for (int k = 2; k <= N; k <<= 1) {
#pragma unroll
    for (int j = k >> 1; j > 0; j >>= 1) {
#pragma unroll
      for (int i = 0; i < N; ++i) {
        int l = i ^ j;
        if (l > i) {
          float x = a[i], y = a[l];
          float mn = fminf(x, y), mx = fmaxf(x, y);
          if ((i & k) == 0) { a[i] = mn; a[l] = mx; }
          else              { a[i] = mx; a[l] = mn; }
        }
      }
    }
  }
}

// Ascending merge of a bitonic sequence (asc half ++ desc half).
template<int N>
__device__ __forceinline__ void bitonic_merge(float (&a)[N]) {
#pragma unroll
  for (int j = N >> 1; j > 0; j >>= 1) {
#pragma unroll
    for (int i = 0; i < N; ++i) {
      int l = i ^ j;
      if (l > i) {
        float x = a[i], y = a[l];
        a[i] = fminf(x, y); a[l] = fmaxf(x, y);
      }
    }
  }
}

// Wave-A emit: all 29 features of window W_ EXCEPT quantiles (slots 8,9 —
// written by wave B). Scan accumulators in scope; c_ is close[T-W_].
#define EMITA(W_, FI_) do {                                                   \
  constexpr float wf_  = (float)(W_);                                         \
  constexpr float inw_ = 1.0f / wf_;                                          \
  constexpr float tm_  = (W_ - 1) * 0.5f;                                     \
  constexpr float tv_  = (float)(((double)(W_) * (W_) - 1.0) / 12.0);         \
  float scm_  = sc * inw_;                                                    \
  float ym_   = cl + scm_;                                                    \
  float yvar_ = fmaxf(sc2 * inw_ - scm_ * scm_, 0.f);                         \
  float stdv_ = sqrtf(yvar_);                                                 \
  float skc_  = (wf_ - 1.f) * sc - sic;                                       \
  float cov_  = skc_ * inw_ - tm_ * scm_;                                     \
  float slope_ = cov_ * (1.0f / tv_);                                         \
  float rsqr_  = cov_ * cov_ * frcp(tv_ * yvar_ + EPSF);                      \
  float resi_  = (cl - ym_) - slope_ * tm_;                                   \
  float cnum_ = sclg - sc * slg * inw_;                                       \
  float cden_ = sqrtf(fmaxf(sc2 - sc * sc * inw_, 0.f) *                      \
                      fmaxf(slg2 - slg * slg * inw_, 0.f)) + EPSF;            \
  float corr_ = cnum_ * frcp(cden_);                                          \
  float dnum_ = srl - sr * sl * inw_;                                         \
  float dden_ = sqrtf(fmaxf(sr2 - sr * sr * inw_, 0.f) *                      \
                      fmaxf(sl2 - sl * sl * inw_, 0.f)) + EPSF;               \
  float cord_ = dnum_ * frcp(dden_);                                          \
  float absd_ = sp + sn;    float ra_ = frcp(absd_ + EPSF);                   \
  float sump_ = sp * ra_,  sumn_ = sn * ra_;                                  \
  float absv_ = dvp + dvn;  float rv_ = frcp(absv_ + EPSF);                   \
  float vsump_ = dvp * rv_, vsumn_ = dvn * rv_;                               \
  float vmean_ = sv * inw_;                                                   \
  float vvar_  = fmaxf(sv2 * inw_ - vmean_ * vmean_, 0.f);                    \
  float wmean_ = sw * inw_;                                                   \
  float wvar_  = fmaxf(sw2 * inw_ - wmean_ * wmean_, 0.f);                    \
  float cntp_ = (float)npos * inw_, cntn_ = (float)nneg * inw_;               \
  float imaxf_ = (float)((W_ - 1) - imax) * inw_;                             \
  float iminf_ = (float)((W_ - 1) - imin) * inw_;                             \
  outr[FI_ + 0]  = c_ * rcl;                                                  \
  outr[FI_ + 1]  = ym_ * rcl;                                                 \
  outr[FI_ + 2]  = stdv_ * rcl;                                               \
  outr[FI_ + 3]  = slope_ * rcl;                                              \
  outr[FI_ + 4]  = rsqr_;                                                     \
  outr[FI_ + 5]  = resi_ * rcl;                                               \
  outr[FI_ + 6]  = hmax * rcl;                                                \
  outr[FI_ + 7]  = lmin * rcl;                                                \
  outr[FI_ + 10] = (float)cntle * inw_;                                       \
  outr[FI_ + 11] = (cl - lmin) * frcp(hmax - lmin + EPSF);                    \
  outr[FI_ + 12] = imaxf_;                                                    \
  outr[FI_ + 13] = iminf_;                                                    \
  outr[FI_ + 14] = imaxf_ - iminf_;                                           \
  outr[FI_ + 15] = corr_;                                                     \
  outr[FI_ + 16] = cord_;                                                     \
  outr[FI_ + 17] = cntp_;                                                     \
  outr[FI_ + 18] = cntn_;                                                     \
  outr[FI_ + 19] = cntp_ - cntn_;                                             \
  outr[FI_ + 20] = sump_;                                                     \
  outr[FI_ + 21] = sumn_;                                                     \
  outr[FI_ + 22] = sump_ - sumn_;                                             \
  outr[FI_ + 23] = vmean_ * rvA;                                              \
  outr[FI_ + 24] = sqrtf(vvar_) * rvA;                                        \
  outr[FI_ + 25] = sqrtf(wvar_) * frcp(wmean_ + EPSF);                        \
  outr[FI_ + 26] = vsump_;                                                    \
  outr[FI_ + 27] = vsumn_;                                                    \
  outr[FI_ + 28] = vsump_ - vsumn_;                                           \
} while (0)

// Wave-B quantile emit from sorted array TA_ (jnp.quantile 'linear').
#define QEMIT(W_, FI_, TA_) do {                                              \
  constexpr int   k8_  = (int)(0.8 * (W_ - 1));                               \
  constexpr float f8_  = (float)(0.8 * (W_ - 1) - k8_);                       \
  constexpr int   k2_  = (int)(0.2 * (W_ - 1));                               \
  constexpr float f2_  = (float)(0.2 * (W_ - 1) - k2_);                       \
  outr[FI_ + 8] = (TA_[k8_] + f8_ * (TA_[k8_ + 1] - TA_[k8_])) * rcl;         \
  outr[FI_ + 9] = (TA_[k2_] + f2_ * (TA_[k2_ + 1] - TA_[k2_])) * rcl;         \
} while (0)

__global__ __launch_bounds__(128, 3)
void factor_kernel(const float* __restrict__ x, float* __restrict__ out, int B)
{
  __shared__ float cs[SPAN], hs[SPAN], ls[SPAN], vs[SPAN], lgs[SPAN];
  __shared__ float ob[CHUNK * OBW];   // 64 x 87 = 22272 B, reused across phases

  const int b    = blockIdx.x / NCH;
  const int ch   = blockIdx.x % NCH;
  const int t0   = WMAX + ch * CHUNK;
  const int clen = min(CHUNK, LP - ch * CHUNK);
  const int base = t0 - WMAX;
  const int span = clen + WMAX;
  const int tid  = threadIdx.x;
  const int tt   = tid & 63;       // point within chunk
  const int role = tid >> 6;       // wave 0 = A (scan), wave 1 = B (sorts)

  // stage raw series
  for (int u = tid; u < span; u += 128) {
    const float* p = x + (size_t)(b * LLEN + base + u) * 6;
    float hv = p[1], lv = p[2], cv = p[3], vv = p[4];
    cs[u] = cv; hs[u] = hv; ls[u] = lv; vs[u] = vv;
    lgs[u] = logf(vv + 1.f);
  }
  __syncthreads();

  const bool active = (tt < clen);
  const int tg = t0 + tt;

  const float* cb = cs  + tt;      // cb[WMAX - i] == series[T - i]
  const float* hb = hs  + tt;
  const float* lb = ls  + tt;
  const float* vb = vs  + tt;
  const float* gb = lgs + tt;

  const float cl  = cb[WMAX];
  const float vol = vb[WMAX];
  const float lgT = gb[WMAX];
  const float rcl = 1.0f / cl;
  const float rvA = 1.0f / (vol + EPSF);

  float* outr = ob + tt * OBW;

  // ---- wave-A scan state (registers, persists across barriers) ----
  float sc = 0.f, sc2 = 0.f, sic = 0.f;
  float sv = 0.f, sv2 = 0.f;
  float slg = 0.f, slg2 = 0.f, sclg = 0.f;
  int   cntle = 0;
  float hmax = -INFINITY, lmin = INFINITY;
  int   imax = 0, imin = 0;
  float sr = 0.f, sr2 = 0.f, sl = 0.f, sl2 = 0.f, srl = 0.f;
  float sw = 0.f, sw2 = 0.f;
  float sp = 0.f, sn = 0.f, dvp = 0.f, dvn = 0.f;
  int   npos = 0, nneg = 0;
  float pv_c = 0.f, pv_v = 0.f;
  float c_ = 0.f, h_ = 0.f, l_ = 0.f, v_ = 0.f, lg_ = 0.f;

  auto load2 = [&](auto ic) {
    constexpr int i = decltype(ic)::value;
    constexpr int q = WMAX - i;
    c_ = cb[q]; v_ = vb[q];
    if constexpr (i < WMAX) { h_ = hb[q]; l_ = lb[q]; lg_ = gb[q]; }
    if constexpr (i >= 1) {
      float d   = pv_c - c_;
      float dv  = pv_v - v_;
      float r   = pv_c * frcp(c_) - 1.f;
      float lcv = __logf(pv_v * frcp(v_ + EPSF) + 1.f);
      float wvv = fabsf(r) * pv_v;
      sr += r;   sr2 = fmaf(r, r, sr2);
      sl += lcv; sl2 = fmaf(lcv, lcv, sl2); srl = fmaf(r, lcv, srl);
      sw += wvv; sw2 = fmaf(wvv, wvv, sw2);
      npos += (d > 0.f) ? 1 : 0;
      nneg += (d < 0.f) ? 1 : 0;
      sp  += fmaxf(d, 0.f);  sn  += fmaxf(-d, 0.f);
      dvp += fmaxf(dv, 0.f); dvn += fmaxf(-dv, 0.f);
    }
  };
  auto p1 = [&](auto ic) {
    constexpr int i = decltype(ic)::value;
    float cd = c_ - cl;
    sc += cd; sc2 = fmaf(cd, cd, sc2); sic = fmaf((float)i, cd, sic);
    cntle += (c_ <= cl) ? 1 : 0;
    if (h_ >= hmax) { hmax = h_; imax = i; }
    if (l_ <= lmin) { lmin = l_; imin = i; }
    sv += v_; sv2 = fmaf(v_, v_, sv2);
    float ld = lg_ - lgT;
    slg += ld; slg2 = fmaf(ld, ld, slg2); sclg = fmaf(cd, ld, sclg);
    pv_c = c_; pv_v = v_;
  };
  auto step = [&](auto ic) { load2(ic); p1(ic); };

  // ================= phase 1 (features 0..70) =================
  if (active) {
    if (role == 0) {
      const float* p = x + (size_t)(b * LLEN + tg) * 6;
      float opn = p[0], vwp = p[5];
      float hi = hb[WMAX], lo = lb[WMAX];
      float hl = hi - lo + EPSF;
      float rhl = frcp(hl);
      float ro  = 1.0f / opn;
      float mx_oc = fmaxf(opn, cl), mn_oc = fminf(opn, cl);
      float body2 = 2.f * cl - hi - lo;
      outr[0]  = (cl - opn) * ro;
      outr[1]  = (hi - lo) * ro;
      outr[2]  = (cl - opn) * rhl;
      outr[3]  = (hi - mx_oc) * ro;
      outr[4]  = (hi - mx_oc) * rhl;
      outr[5]  = (mn_oc - lo) * ro;
      outr[6]  = (mn_oc - lo) * rhl;
      outr[7]  = body2 * ro;
      outr[8]  = body2 * rhl;
      outr[9]  = opn * rcl;
      outr[10] = hi * rcl;
      outr[11] = lo * rcl;
      outr[12] = vwp * rcl;

      unroll_for<0, 5>(step);                     // i = 0..4
      load2(std::integral_constant<int, 5>{});
      EMITA(5, 13);
      p1(std::integral_constant<int, 5>{});
      unroll_for<6, 4>(step);                     // i = 6..9
      load2(std::integral_constant<int, 10>{});
      EMITA(10, 42);
      p1(std::integral_constant<int, 10>{});
    } else {
      // wave B: quantiles for w5, w10
      float t8[8];
      unroll_for<0, 8>([&](auto qi) {
        constexpr int i = decltype(qi)::value;
        t8[i] = (i < 5) ? cb[WMAX - i] : INFINITY;
      });
      bitonic_sort<8>(t8);
      QEMIT(5, 13, t8);
      float t16[16];
      unroll_for<0, 16>([&](auto qi) {
        constexpr int i = decltype(qi)::value;
        t16[i] = (i < 10) ? cb[WMAX - i] : INFINITY;
      });
      bitonic_sort<16>(t16);
      QEMIT(10, 42, t16);
    }
  }
  __syncthreads();

  // ---- flush phase 1: features 0..70 ----
  {
    float* gout = out + ((size_t)b * LP + ch * CHUNK) * NF;
    const int total = clen * PH1;
    for (int n = tid; n < total; n += 128) {
      int r = n / PH1, cc = n - r * PH1;
      gout[(size_t)r * NF + cc] = ob[r * OBW + cc];
    }
  }
  __syncthreads();

  // ================= phase 2 (features 71..157) =================
  if (active) {
    if (role == 0) {
      unroll_for<11, 9>(step);                    // i = 11..19
      load2(std::integral_constant<int, 20>{});
      EMITA(20, 0);                               // global 71..99
      p1(std::integral_constant<int, 20>{});
      unroll_for<21, 9>(step);                    // i = 21..29
      load2(std::integral_constant<int, 30>{});
      EMITA(30, 29);                              // global 100..128
      p1(std::integral_constant<int, 30>{});
      unroll_for<31, 29>(step);                   // i = 31..59
      load2(std::integral_constant<int, 60>{});
      EMITA(60, 58);                              // global 129..157
    } else {
      // wave B: quantiles for w20, w30, w60
      {
        float t32[32];
        unroll_for<0, 32>([&](auto qi) {
          constexpr int i = decltype(qi)::value;
          t32[i] = (i < 20) ? cb[WMAX - i] : INFINITY;
        });
        bitonic_sort<32>(t32);
        QEMIT(20, 0, t32);
      }
      float s30[32];
      unroll_for<0, 32>([&](auto qi) {
        constexpr int i = decltype(qi)::value;
        s30[i] = (i < 30) ? cb[WMAX - i] : INFINITY;
      });
      bitonic_sort<32>(s30);
      QEMIT(30, 29, s30);
      // w60: sorted(c[0..29]) in s30; sort c[30..59], bitonic-merge.
      float m64[64];
      unroll_for<0, 32>([&](auto qi) {
        constexpr int i = decltype(qi)::value;
        m64[i] = s30[i];
      });
      {
        float e32[32];
        unroll_for<0, 32>([&](auto qi) {
          constexpr int i = decltype(qi)::value;
          e32[i] = (i < 30) ? cb[WMAX - 30 - i] : INFINITY;
        });
        bitonic_sort<32>(e32);
        unroll_for<0, 32>([&](auto qi) {
          constexpr int i = decltype(qi)::value;
          m64[32 + i] = e32[31 - i];              // descending half
        });
      }
      bitonic_merge<64>(m64);
      QEMIT(60, 58, m64);
    }
  }
  __syncthreads();

  // ---- flush phase 2: features 71..157 ----
  {
    float* gout = out + ((size_t)b * LP + ch * CHUNK) * NF + PH1;
    const int total = clen * OBW;
    for (int n = tid; n < total; n += 128) {
      int r = n / OBW, cc = n - r * OBW;
      gout[(size_t)r * NF + cc] = ob[n];
    }
  }
}

extern "C" void kernel_launch(void* const* d_in, const int* in_sizes, int n_in,
                              void* d_out, int out_size, void* d_ws, size_t ws_size,
                              hipStream_t stream) {
  const float* x = (const float*)d_in[0];
  float* out = (float*)d_out;
  int B = in_sizes[0] / (LLEN * 6);   // 128
  dim3 grid(B * NCH), block(128);
  hipLaunchKernelGGL(factor_kernel, grid, block, 0, stream, x, out, B);
}

// Round 9
// 45.246 us; speedup vs baseline: 1.6945x; 1.0931x over previous
//
#include <hip/hip_runtime.h>
#include <math.h>
#include <utility>

#define EPSF 1e-12f

constexpr int LLEN = 1024;
constexpr int WMAX = 60;
constexpr int LP   = 964;
constexpr int NF   = 158;
constexpr int CHUNK = 64;
constexpr int SPAN  = CHUNK + WMAX; // 124
constexpr int NCH   = (LP + CHUNK - 1) / CHUNK; // 16
constexpr int OBW   = 87;           // LDS row stride; 87%32=23 coprime w/ 32
constexpr int PH1   = 71;           // phase-1 width: base(13)+w5(29)+w10(29)
constexpr int NT    = 192;          // 3 waves: A(pass1) B(sorts) C(pass2)

__device__ __forceinline__ float frcp(float x) {
#if __has_builtin(__builtin_amdgcn_rcpf)
  return __builtin_amdgcn_rcpf(x);
#else
  return 1.0f / x;
#endif
}

template<int I0, class F, int... Is>
__device__ __forceinline__ void unroll_impl(F&& f, std::integer_sequence<int, Is...>) {
  (f(std::integral_constant<int, I0 + Is>{}), ...);
}
template<int I0, int N, class F>
__device__ __forceinline__ void unroll_for(F&& f) {
  unroll_impl<I0>(f, std::make_integer_sequence<int, N>{});
}

template<int N>
__device__ __forceinline__ void bitonic_sort(float (&a)[N]) {
#pragma unroll
  for (int k = 2; k <= N; k <<= 1) {
#pragma unroll
    for (int j = k >> 1; j > 0; j >>= 1) {
#pragma unroll
      for (int i = 0; i < N; ++i) {
        int l = i ^ j;
        if (l > i) {
          float x = a[i], y = a[l];
          float mn = fminf(x, y), mx = fmaxf(x, y);
          if ((i & k) == 0) { a[i] = mn; a[l] = mx; }
          else              { a[i] = mx; a[l] = mn; }
        }
      }
    }
  }
}

// Ascending merge of a bitonic sequence (asc half ++ desc half).
template<int N>
__device__ __forceinline__ void bitonic_merge(float (&a)[N]) {
#pragma unroll
  for (int j = N >> 1; j > 0; j >>= 1) {
#pragma unroll
    for (int i = 0; i < N; ++i) {
      int l = i ^ j;
      if (l > i) {
        float x = a[i], y = a[l];
        a[i] = fminf(x, y); a[l] = fmaxf(x, y);
      }
    }
  }
}

// Wave-A emit: pass1-derived features of window W_ (slots 0-7,10-15,23,24).
#define EMITA(W_, FI_) do {                                                   \
  constexpr float wf_  = (float)(W_);                                         \
  constexpr float inw_ = 1.0f / wf_;                                          \
  constexpr float tm_  = (W_ - 1) * 0.5f;                                     \
  constexpr float tv_  = (float)(((double)(W_) * (W_) - 1.0) / 12.0);         \
  float scm_  = sc * inw_;                                                    \
  float ym_   = cl + scm_;                                                    \
  float yvar_ = fmaxf(sc2 * inw_ - scm_ * scm_, 0.f);                         \
  float stdv_ = sqrtf(yvar_);                                                 \
  float skc_  = (wf_ - 1.f) * sc - sic;                                       \
  float cov_  = skc_ * inw_ - tm_ * scm_;                                     \
  float slope_ = cov_ * (1.0f / tv_);                                         \
  float rsqr_  = cov_ * cov_ * frcp(tv_ * yvar_ + EPSF);                      \
  float resi_  = (cl - ym_) - slope_ * tm_;                                   \
  float cnum_ = sclg - sc * slg * inw_;                                       \
  float cden_ = sqrtf(fmaxf(sc2 - sc * sc * inw_, 0.f) *                      \
                      fmaxf(slg2 - slg * slg * inw_, 0.f)) + EPSF;            \
  float corr_ = cnum_ * frcp(cden_);                                          \
  float vmean_ = sv * inw_;                                                   \
  float vvar_  = fmaxf(sv2 * inw_ - vmean_ * vmean_, 0.f);                    \
  float imaxf_ = (float)((W_ - 1) - imax) * inw_;                             \
  float iminf_ = (float)((W_ - 1) - imin) * inw_;                             \
  outr[FI_ + 0]  = c_ * rcl;                                                  \
  outr[FI_ + 1]  = ym_ * rcl;                                                 \
  outr[FI_ + 2]  = stdv_ * rcl;                                               \
  outr[FI_ + 3]  = slope_ * rcl;                                              \
  outr[FI_ + 4]  = rsqr_;                                                     \
  outr[FI_ + 5]  = resi_ * rcl;                                               \
  outr[FI_ + 6]  = hmax * rcl;                                                \
  outr[FI_ + 7]  = lmin * rcl;                                                \
  outr[FI_ + 10] = (float)cntle * inw_;                                       \
  outr[FI_ + 11] = (cl - lmin) * frcp(hmax - lmin + EPSF);                    \
  outr[FI_ + 12] = imaxf_;                                                    \
  outr[FI_ + 13] = iminf_;                                                    \
  outr[FI_ + 14] = imaxf_ - iminf_;                                           \
  outr[FI_ + 15] = corr_;                                                     \
  outr[FI_ + 23] = vmean_ * rvA;                                              \
  outr[FI_ + 24] = sqrtf(vvar_) * rvA;                                        \
} while (0)

// Wave-C emit: pass2-derived features (slots 16-22,25-28).
#define EMITC(W_, FI_) do {                                                   \
  constexpr float inw_ = 1.0f / (float)(W_);                                  \
  float dnum_ = srl - sr * sl * inw_;                                         \
  float dden_ = sqrtf(fmaxf(sr2 - sr * sr * inw_, 0.f) *                      \
                      fmaxf(sl2 - sl * sl * inw_, 0.f)) + EPSF;               \
  float cord_ = dnum_ * frcp(dden_);                                          \
  float ra_ = frcp(sp + sn + EPSF);                                           \
  float sump_ = sp * ra_,  sumn_ = sn * ra_;                                  \
  float rv_ = frcp(dvp + dvn + EPSF);                                         \
  float vsump_ = dvp * rv_, vsumn_ = dvn * rv_;                               \
  float wmean_ = sw * inw_;                                                   \
  float wvar_  = fmaxf(sw2 * inw_ - wmean_ * wmean_, 0.f);                    \
  float cntp_ = (float)npos * inw_, cntn_ = (float)nneg * inw_;               \
  outr[FI_ + 16] = cord_;                                                     \
  outr[FI_ + 17] = cntp_;                                                     \
  outr[FI_ + 18] = cntn_;                                                     \
  outr[FI_ + 19] = cntp_ - cntn_;                                             \
  outr[FI_ + 20] = sump_;                                                     \
  outr[FI_ + 21] = sumn_;                                                     \
  outr[FI_ + 22] = sump_ - sumn_;                                             \
  outr[FI_ + 25] = sqrtf(wvar_) * frcp(wmean_ + EPSF);                        \
  outr[FI_ + 26] = vsump_;                                                    \
  outr[FI_ + 27] = vsumn_;                                                    \
  outr[FI_ + 28] = vsump_ - vsumn_;                                           \
} while (0)

// Wave-B quantile emit from sorted array TA_ (jnp.quantile 'linear').
#define QEMIT(W_, FI_, TA_) do {                                              \
  constexpr int   k8_  = (int)(0.8 * (W_ - 1));                               \
  constexpr float f8_  = (float)(0.8 * (W_ - 1) - k8_);                       \
  constexpr int   k2_  = (int)(0.2 * (W_ - 1));                               \
  constexpr float f2_  = (float)(0.2 * (W_ - 1) - k2_);                       \
  outr[FI_ + 8] = (TA_[k8_] + f8_ * (TA_[k8_ + 1] - TA_[k8_])) * rcl;         \
  outr[FI_ + 9] = (TA_[k2_] + f2_ * (TA_[k2_ + 1] - TA_[k2_])) * rcl;         \
} while (0)

__global__ __launch_bounds__(NT, 4)
void factor_kernel(const float* __restrict__ x, float* __restrict__ out, int B)
{
  __shared__ float cs[SPAN], hs[SPAN], ls[SPAN], vs[SPAN], lgs[SPAN];
  __shared__ float ob[CHUNK * OBW];   // 64 x 87 = 22272 B, reused across phases

  const int b    = blockIdx.x / NCH;
  const int ch   = blockIdx.x % NCH;
  const int t0   = WMAX + ch * CHUNK;
  const int clen = min(CHUNK, LP - ch * CHUNK);
  const int base = t0 - WMAX;
  const int span = clen + WMAX;
  const int tid  = threadIdx.x;
  const int tt   = tid & 63;       // point within chunk
  const int role = tid >> 6;       // 0=A(pass1) 1=B(sorts) 2=C(pass2)

  // stage raw series
  for (int u = tid; u < span; u += NT) {
    const float* p = x + (size_t)(b * LLEN + base + u) * 6;
    float hv = p[1], lv = p[2], cv = p[3], vv = p[4];
    cs[u] = cv; hs[u] = hv; ls[u] = lv; vs[u] = vv;
    lgs[u] = logf(vv + 1.f);
  }
  __syncthreads();

  const bool active = (tt < clen);
  const int tg = t0 + tt;

  const float* cb = cs  + tt;      // cb[WMAX - i] == series[T - i]
  const float* hb = hs  + tt;
  const float* lb = ls  + tt;
  const float* vb = vs  + tt;
  const float* gb = lgs + tt;

  const float cl  = cb[WMAX];
  const float vol = vb[WMAX];
  const float lgT = gb[WMAX];
  const float rcl = 1.0f / cl;
  const float rvA = 1.0f / (vol + EPSF);

  float* outr = ob + tt * OBW;

  // ---- scan state (per-role subsets used; registers persist across barriers) ----
  float sc = 0.f, sc2 = 0.f, sic = 0.f;
  float sv = 0.f, sv2 = 0.f;
  float slg = 0.f, slg2 = 0.f, sclg = 0.f;
  int   cntle = 0;
  float hmax = -INFINITY, lmin = INFINITY;
  int   imax = 0, imin = 0;
  float sr = 0.f, sr2 = 0.f, sl = 0.f, sl2 = 0.f, srl = 0.f;
  float sw = 0.f, sw2 = 0.f;
  float sp = 0.f, sn = 0.f, dvp = 0.f, dvn = 0.f;
  int   npos = 0, nneg = 0;
  float pv_c = 0.f, pv_v = 0.f;
  float c_ = 0.f, h_ = 0.f, l_ = 0.f, v_ = 0.f, lg_ = 0.f;

  // ---- wave A: pass1 ----
  auto loadA = [&](auto ic) {
    constexpr int i = decltype(ic)::value;
    constexpr int q = WMAX - i;
    c_ = cb[q];
    if constexpr (i < WMAX) { h_ = hb[q]; l_ = lb[q]; v_ = vb[q]; lg_ = gb[q]; }
  };
  auto p1A = [&](auto ic) {
    constexpr int i = decltype(ic)::value;
    float cd = c_ - cl;
    sc += cd; sc2 = fmaf(cd, cd, sc2); sic = fmaf((float)i, cd, sic);
    cntle += (c_ <= cl) ? 1 : 0;
    if (h_ >= hmax) { hmax = h_; imax = i; }
    if (l_ <= lmin) { lmin = l_; imin = i; }
    sv += v_; sv2 = fmaf(v_, v_, sv2);
    float ld = lg_ - lgT;
    slg += ld; slg2 = fmaf(ld, ld, slg2); sclg = fmaf(cd, ld, sclg);
  };
  auto stepA = [&](auto ic) { loadA(ic); p1A(ic); };

  // ---- wave C: pass2 ----
  auto pairC = [&](auto ic) {
    constexpr int i = decltype(ic)::value;
    constexpr int q = WMAX - i;
    c_ = cb[q]; v_ = vb[q];
    if constexpr (i >= 1) {
      float d   = pv_c - c_;
      float dv  = pv_v - v_;
      float r   = pv_c * frcp(c_) - 1.f;
      float lcv = __logf(pv_v * frcp(v_ + EPSF) + 1.f);
      float wvv = fabsf(r) * pv_v;
      sr += r;   sr2 = fmaf(r, r, sr2);
      sl += lcv; sl2 = fmaf(lcv, lcv, sl2); srl = fmaf(r, lcv, srl);
      sw += wvv; sw2 = fmaf(wvv, wvv, sw2);
      npos += (d > 0.f) ? 1 : 0;
      nneg += (d < 0.f) ? 1 : 0;
      sp  += fmaxf(d, 0.f);  sn  += fmaxf(-d, 0.f);
      dvp += fmaxf(dv, 0.f); dvn += fmaxf(-dv, 0.f);
    }
  };
  auto stepC = [&](auto ic) { pairC(ic); pv_c = c_; pv_v = v_; };

  // ================= phase 1 (features 0..70) =================
  if (active) {
    if (role == 0) {
      const float* p = x + (size_t)(b * LLEN + tg) * 6;
      float opn = p[0], vwp = p[5];
      float hi = hb[WMAX], lo = lb[WMAX];
      float hl = hi - lo + EPSF;
      float rhl = frcp(hl);
      float ro  = 1.0f / opn;
      float mx_oc = fmaxf(opn, cl), mn_oc = fminf(opn, cl);
      float body2 = 2.f * cl - hi - lo;
      outr[0]  = (cl - opn) * ro;
      outr[1]  = (hi - lo) * ro;
      outr[2]  = (cl - opn) * rhl;
      outr[3]  = (hi - mx_oc) * ro;
      outr[4]  = (hi - mx_oc) * rhl;
      outr[5]  = (mn_oc - lo) * ro;
      outr[6]  = (mn_oc - lo) * rhl;
      outr[7]  = body2 * ro;
      outr[8]  = body2 * rhl;
      outr[9]  = opn * rcl;
      outr[10] = hi * rcl;
      outr[11] = lo * rcl;
      outr[12] = vwp * rcl;

      unroll_for<0, 5>(stepA);                    // i = 0..4
      loadA(std::integral_constant<int, 5>{});
      EMITA(5, 13);
      p1A(std::integral_constant<int, 5>{});
      unroll_for<6, 4>(stepA);                    // i = 6..9
      loadA(std::integral_constant<int, 10>{});
      EMITA(10, 42);
      p1A(std::integral_constant<int, 10>{});
    } else if (role == 1) {
      float t8[8];
      unroll_for<0, 8>([&](auto qi) {
        constexpr int i = decltype(qi)::value;
        t8[i] = (i < 5) ? cb[WMAX - i] : INFINITY;
      });
      bitonic_sort<8>(t8);
      QEMIT(5, 13, t8);
      float t16[16];
      unroll_for<0, 16>([&](auto qi) {
        constexpr int i = decltype(qi)::value;
        t16[i] = (i < 10) ? cb[WMAX - i] : INFINITY;
      });
      bitonic_sort<16>(t16);
      QEMIT(10, 42, t16);
    } else {
      unroll_for<0, 5>(stepC);                    // i = 0..4 (pairs 1..4)
      pairC(std::integral_constant<int, 5>{});
      EMITC(5, 13);
      pv_c = c_; pv_v = v_;
      unroll_for<6, 4>(stepC);                    // i = 6..9
      pairC(std::integral_constant<int, 10>{});
      EMITC(10, 42);
      pv_c = c_; pv_v = v_;
    }
  }
  __syncthreads();

  // ---- flush phase 1: features 0..70 ----
  {
    float* gout = out + ((size_t)b * LP + ch * CHUNK) * NF;
    const int total = clen * PH1;
    for (int n = tid; n < total; n += NT) {
      int r = n / PH1, cc = n - r * PH1;
      gout[(size_t)r * NF + cc] = ob[r * OBW + cc];
    }
  }
  __syncthreads();

  // ================= phase 2 (features 71..157) =================
  if (active) {
    if (role == 0) {
      unroll_for<11, 9>(stepA);                   // i = 11..19
      loadA(std::integral_constant<int, 20>{});
      EMITA(20, 0);                               // global 71..99
      p1A(std::integral_constant<int, 20>{});
      unroll_for<21, 9>(stepA);                   // i = 21..29
      loadA(std::integral_constant<int, 30>{});
      EMITA(30, 29);                              // global 100..128
      p1A(std::integral_constant<int, 30>{});
      unroll_for<31, 29>(stepA);                  // i = 31..59
      loadA(std::integral_constant<int, 60>{});
      EMITA(60, 58);                              // global 129..157
    } else if (role == 1) {
      {
        float t32[32];
        unroll_for<0, 32>([&](auto qi) {
          constexpr int i = decltype(qi)::value;
          t32[i] = (i < 20) ? cb[WMAX - i] : INFINITY;
        });
        bitonic_sort<32>(t32);
        QEMIT(20, 0, t32);
      }
      float s30[32];
      unroll_for<0, 32>([&](auto qi) {
        constexpr int i = decltype(qi)::value;
        s30[i] = (i < 30) ? cb[WMAX - i] : INFINITY;
      });
      bitonic_sort<32>(s30);
      QEMIT(30, 29, s30);
      // w60: sorted(c[0..29]) in s30; sort c[30..59] desc; bitonic-merge.
      float m64[64];
      unroll_for<0, 32>([&](auto qi) {
        constexpr int i = decltype(qi)::value;
        m64[i] = s30[i];
      });
      {
        float e32[32];
        unroll_for<0, 32>([&](auto qi) {
          constexpr int i = decltype(qi)::value;
          e32[i] = (i < 30) ? cb[WMAX - 30 - i] : INFINITY;
        });
        bitonic_sort<32>(e32);
        unroll_for<0, 32>([&](auto qi) {
          constexpr int i = decltype(qi)::value;
          m64[32 + i] = e32[31 - i];              // descending half
        });
      }
      bitonic_merge<64>(m64);
      QEMIT(60, 58, m64);
    } else {
      unroll_for<11, 9>(stepC);                   // i = 11..19
      pairC(std::integral_constant<int, 20>{});
      EMITC(20, 0);
      pv_c = c_; pv_v = v_;
      unroll_for<21, 9>(stepC);                   // i = 21..29
      pairC(std::integral_constant<int, 30>{});
      EMITC(30, 29);
      pv_c = c_; pv_v = v_;
      unroll_for<31, 29>(stepC);                  // i = 31..59
      pairC(std::integral_constant<int, 60>{});
      EMITC(60, 58);
    }
  }
  __syncthreads();

  // ---- flush phase 2: features 71..157 ----
  {
    float* gout = out + ((size_t)b * LP + ch * CHUNK) * NF + PH1;
    const int total = clen * OBW;
    for (int n = tid; n < total; n += NT) {
      int r = n / OBW, cc = n - r * OBW;
      gout[(size_t)r * NF + cc] = ob[n];
    }
  }
}

extern "C" void kernel_launch(void* const* d_in, const int* in_sizes, int n_in,
                              void* d_out, int out_size, void* d_ws, size_t ws_size,
                              hipStream_t stream) {
  const float* x = (const float*)d_in[0];
  float* out = (float*)d_out;
  int B = in_sizes[0] / (LLEN * 6);   // 128
  dim3 grid(B * NCH), block(NT);
  hipLaunchKernelGGL(factor_kernel, grid, block, 0, stream, x, out, B);
}